// Round 6
// baseline (853.200 us; speedup 1.0000x reference)
//
#include <hip/hip_runtime.h>

typedef __attribute__((ext_vector_type(8))) short short8;
typedef __attribute__((ext_vector_type(4))) float floatx4;

// Original x layout (element offsets): b<<24 | c<<18 | d<<14 | h<<10 | w<<6 | p<<4 | q<<2 | r
// Transposed xT layout (bf16): offset = b<<24 | s<<6 | c, s = d<<14|...|r (same packing).
// Image axes: 0=d 1=h 2=w. Patch axes handled by patch_fused (p,q,r).
// GEMM k = a*64 + c (matches W.reshape(S,C,S,C)).

__device__ __forceinline__ unsigned short f2bf(float f){
  unsigned int u = __float_as_uint(f);
  u += 0x7FFFu + ((u >> 16) & 1u);   // RNE
  return (unsigned short)(u >> 16);
}

// m -> element offset in ORIGINAL layout, given axis value a and channel c (image stores)
template<int AX>
__device__ __forceinline__ int tidx(int m, int a, int c){
  if      (AX==0){ int b=m>>14, t=m&16383;                         return (b<<24)|(c<<18)|(a<<14)|t; }
  else if (AX==1){ int b=m>>14, d=(m>>10)&15, t=m&1023;            return (b<<24)|(c<<18)|(d<<14)|(a<<10)|t; }
  else           { int b=m>>14, d=(m>>10)&15, h=(m>>6)&15, t=m&63; return (b<<24)|(c<<18)|(d<<14)|(h<<10)|(a<<6)|t; }
}

// m -> base element offset in TRANSPOSED layout (a=0, c=0); add a*SA + c.
template<int AX>
__device__ __forceinline__ int srcbase(int m){
  if      (AX==0) return ((m>>14)<<24) | (((m>>10)&15)<<16) | (((m>>6)&15)<<12) | ((m&63)<<6);
  else if (AX==1) return ((m>>14)<<24) | (((m>>10)&15)<<20) | (((m>>6)&15)<<12) | ((m&63)<<6);
  else            return ((m>>14)<<24) | (((m>>10)&15)<<20) | (((m>>6)&15)<<16) | ((m&63)<<6);
}

#define ASYNC_CP16(g, l) \
  __builtin_amdgcn_global_load_lds( \
      (const __attribute__((address_space(1))) unsigned int*)(g), \
      (__attribute__((address_space(3))) unsigned int*)(l), 16, 0, 0)

// ---------------- fused weight cast + bias precombine ----------------
// blocks [0,6144): big W cast; [6144,6528): small W cast;
// [6528,7552): Bimg[d][h][w][c] = bd+bh+bw; [7552,7616): Bpat[t][c] = bpd+bph+bpw
__global__ __launch_bounds__(256) void castw_all(
    const float* __restrict__ wa, const float* __restrict__ wb, const float* __restrict__ wc,
    const float* __restrict__ wd_, const float* __restrict__ we, const float* __restrict__ wf,
    const float* __restrict__ bd_, const float* __restrict__ bh_, const float* __restrict__ bw_,
    const float* __restrict__ bpd_, const float* __restrict__ bph_, const float* __restrict__ bpw_,
    unsigned short* oa, unsigned short* ob, unsigned short* oc,
    unsigned short* od, unsigned short* oe, unsigned short* of_,
    float* __restrict__ Bimg, float* __restrict__ Bpat){
  int blk = blockIdx.x;
  if (blk < 6528){
    const float* src; unsigned short* dst; int idx;
    if (blk < 6144){ int wsel = blk >> 11, loc = blk & 2047;
      src = wsel==0?wa:(wsel==1?wb:wc); dst = wsel==0?oa:(wsel==1?ob:oc);
      idx = loc*256 + threadIdx.x; }
    else { int b2 = blk - 6144, wsel = b2 >> 7, loc = b2 & 127;
      src = wsel==0?wd_:(wsel==1?we:wf); dst = wsel==0?od:(wsel==1?oe:of_);
      idx = loc*256 + threadIdx.x; }
    float2 v = ((const float2*)src)[idx];
    ((unsigned int*)dst)[idx] = (unsigned int)f2bf(v.x) | ((unsigned int)f2bf(v.y) << 16);
  } else if (blk < 7552){
    int idx = (blk - 6528)*256 + threadIdx.x;     // [d][h][w][c]
    int c = idx & 63, wv = (idx>>6)&15, hv = (idx>>10)&15, dv = idx>>14;
    Bimg[idx] = bd_[dv*64+c] + bh_[hv*64+c] + bw_[wv*64+c];
  } else {
    int idx = (blk - 7552)*256 + threadIdx.x;     // [t][c], t = p<<4|q<<2|r
    int c = idx & 63, tt = idx>>6;
    int p = tt>>4, q = (tt>>2)&3, r = tt&3;
    Bpat[idx] = bpd_[p*64+c] + bph_[q*64+c] + bpw_[r*64+c];
  }
}

// ---------------- transpose: x fp32 [b][c][s] -> xT bf16 [b][s][c] ----------------
__global__ __launch_bounds__(256) void transpose_cx(const float* __restrict__ x,
                                                    unsigned short* __restrict__ xt){
  __shared__ float T[64][65];
  int b  = blockIdx.x >> 12;
  int s0 = (blockIdx.x & 4095) * 64;
  int t = threadIdx.x;
  int cr = t >> 4, sq = t & 15;
  #pragma unroll
  for (int it = 0; it < 4; it++){
    int c = it*16 + cr;
    float4 v = *(const float4*)(x + (b<<24) + (c<<18) + s0 + sq*4);
    T[c][sq*4+0]=v.x; T[c][sq*4+1]=v.y; T[c][sq*4+2]=v.z; T[c][sq*4+3]=v.w;
  }
  __syncthreads();
  int sw = t >> 2, cq = t & 3;
  unsigned int pk[8];
  #pragma unroll
  for (int i=0;i<8;i++){
    float f0 = T[cq*16 + 2*i    ][sw];
    float f1 = T[cq*16 + 2*i + 1][sw];
    pk[i] = (unsigned int)f2bf(f0) | ((unsigned int)f2bf(f1) << 16);
  }
  uint4* dst = (uint4*)(xt + (b<<24) + ((s0 + sw)<<6) + cq*16);
  dst[0] = make_uint4(pk[0],pk[1],pk[2],pk[3]);
  dst[1] = make_uint4(pk[4],pk[5],pk[6],pk[7]);
}

// ---------------- fused patch kernel: 3 patch axes, one pass over out ----------------
// Block owns 2 consecutive patches (contiguous 8192 els of xT), staged ONCE into LDS
// (chunk-XOR swizzled so ds_read_b128 for all 3 axes' access patterns is <=2-way).
// Wave w owns own-axis output coord a'=w for each axis. LDS fp32 acc stride 65.
template<int AXI, bool FIRST>
__device__ __forceinline__ void patch_axis(const unsigned short* Xs,
                                           const unsigned short* __restrict__ W,
                                           float* AccL, int w, int l16, int q8){
  floatx4 acc[4][2];
  #pragma unroll
  for (int nt=0;nt<4;nt++)
    #pragma unroll
    for (int mt=0;mt<2;mt++) acc[nt][mt] = (floatx4){0.f,0.f,0.f,0.f};

  #pragma unroll 2
  for (int kit = 0; kit < 8; kit++){
    int a = kit >> 1;
    short8 bf[2], af[4];
    int u = (AXI==0) ? (a*16 + l16)
          : (AXI==1) ? ((l16>>2)*16 + a*4 + (l16&3))
                     : ((l16>>2)*16 + (l16&3)*4 + a);
    int jg = ((kit & 1) << 2) + q8;                 // global 16B-chunk index within row
    #pragma unroll
    for (int mt = 0; mt < 2; mt++){
      int r = mt*64 + u;
      int j = jg ^ ((r ^ (r >> 3)) & 7);           // same involution as staging
      bf[mt] = *(const short8*)(Xs + r*64 + j*8);
    }
    #pragma unroll
    for (int nt = 0; nt < 4; nt++){
      int n = w*64 + nt*16 + l16;
      af[nt] = *(const short8*)(W + n*256 + kit*32 + q8*8);
    }
    #pragma unroll
    for (int nt=0; nt<4; nt++)
      #pragma unroll
      for (int mt=0; mt<2; mt++)
        acc[nt][mt] = __builtin_amdgcn_mfma_f32_16x16x32_bf16(af[nt], bf[mt], acc[nt][mt], 0,0,0);
  }

  int uo = (AXI==0) ? (w*16 + l16)
         : (AXI==1) ? ((l16>>2)*16 + w*4 + (l16&3))
                    : ((l16>>2)*16 + (l16&3)*4 + w);
  #pragma unroll
  for (int nt=0; nt<4; nt++)
    #pragma unroll
    for (int mt=0; mt<2; mt++){
      float* p = AccL + (mt*64 + uo)*65 + nt*16 + q8*4;
      #pragma unroll
      for (int rg=0; rg<4; rg++){
        if (FIRST) p[rg]  = acc[nt][mt][rg];
        else       p[rg] += acc[nt][mt][rg];
      }
    }
}

__global__ __launch_bounds__(256) void patch_fused(const unsigned short* __restrict__ xt,
    const unsigned short* __restrict__ Wp_, const unsigned short* __restrict__ Wq_,
    const unsigned short* __restrict__ Wr_, float* __restrict__ out){
  __shared__ float AccL[2*64*65];            // 33.28 KB
  __shared__ unsigned short Xs[8192];        // 16 KB: 128 rows x 64 shorts, chunk-swizzled
  int pp = blockIdx.x;
  int b = pp >> 11, dpair = pp & 2047;
  const unsigned short* xp = xt + (b<<24) + dpair*8192;
  int t = threadIdx.x, w = t>>6, lane = t&63, q8 = lane>>4, l16 = lane&15;

  // stage 2 patches (1024 x 16B chunks) via async copy; inverse-swizzled global source,
  // linear LDS dest (wave-uniform base + lane*16 appended by HW)
  #pragma unroll
  for (int i = 0; i < 4; i++){
    int L = i*256 + t;                       // LDS chunk index this lane fills
    int r = L >> 3, jl = L & 7;
    int jg = jl ^ ((r ^ (r >> 3)) & 7);
    ASYNC_CP16(xp + r*64 + jg*8, Xs + i*2048 + w*512);
  }
  __syncthreads();

  patch_axis<0,true >(Xs, Wp_, AccL, w, l16, q8);
  __syncthreads();
  patch_axis<1,false>(Xs, Wq_, AccL, w, l16, q8);
  __syncthreads();
  patch_axis<2,false>(Xs, Wr_, AccL, w, l16, q8);
  __syncthreads();

  int sbase = dpair*128;                     // s = dpair*2*64 + pt*64 + u
  #pragma unroll
  for (int it = 0; it < 32; it++){
    int lin = it*256 + t;
    int c = lin >> 7, rem = lin & 127, pt = rem >> 6, u = rem & 63;
    out[(b<<24) | (c<<18) | (sbase + pt*64 + u)] = AccL[(pt*64+u)*65 + c];
  }
}

// ---------------- image GEMM: out[n=(a',c'), m] += sum_k W[n][k] * xT[m][k] ----------------
// 256x256 tile, 512 threads (8 waves, wave sub-tile 128m x 64n). The R1/R3/R4 rounds all
// pinned at ~28 B/cy/CU VMEM return bandwidth -> the lever is bytes/output: 256^2 stages
// 16 B/elem (vs 32 at 128^2). Counted-vmcnt double-buffer (R4-verified): compute tile t
// while t+1 in flight, t+2 issued after t's buffer frees; s_waitcnt vmcnt(8) keeps the
// next tile's 8 loads in flight -- never drain-0 in the main loop.
// XCD grouping: the 4 nt-blocks sharing one X stripe land on the same XCD (stride-8).
// BK=64, 128B LDS rows, slot-XOR swizzle j ^= (r&7): ds_read_b128 is 2-way max (free).
// EPI: fused final epilogue  out = x + leaky(out + acc + Bimg + Bpat)  (AX==2 only).
#define WAITV8 asm volatile("s_waitcnt vmcnt(8)" ::: "memory")
#define WAITV0 asm volatile("s_waitcnt vmcnt(0)" ::: "memory")

template<int AX, int EPI>
__global__ __launch_bounds__(512, 2) void gemm_img(const unsigned short* __restrict__ xt,
                                                   const unsigned short* __restrict__ Wbf,
                                                   float* __restrict__ out,
                                                   const float* __restrict__ x,
                                                   const float* __restrict__ Bimg,
                                                   const float* __restrict__ Bpat){
  constexpr int K  = 1024;
  constexpr int SA = (AX==0)?(1<<20):(AX==1)?(1<<16):(1<<12);
  // 512 blocks = 128 mt x 4 nt; same-mt quads share an XCD (bids differ by 8).
  int bid = blockIdx.x;
  int mt = (bid >> 5) * 8 + (bid & 7);     // 0..127
  int nt = (bid >> 3) & 3;                 // 0..3

  __shared__ unsigned short Xs0[256*64], Ws0[256*64];   // 32 KB each
  __shared__ unsigned short Xs1[256*64], Ws1[256*64];   // 128 KB total -> 1 block/CU

  int t = threadIdx.x, lane = t & 63, wid = t >> 6;
  int wnb = (wid & 3) << 6;                // wave n offset: 0,64,128,192
  int wmb = (wid >> 2) << 7;               // wave m offset: 0,128
  int q8 = lane >> 4, l16 = lane & 15;

  floatx4 acc[4][8];
  #pragma unroll
  for (int i=0;i<4;i++)
    #pragma unroll
    for (int j=0;j<8;j++) acc[i][j] = (floatx4){0.f,0.f,0.f,0.f};

  const unsigned short* Wp = Wbf + (size_t)nt*256*K;

  // staging: thread t fills LDS chunk L = c*512 + t (c = 0..3);
  // row r = c*64 + (t>>3), local slot jl = t&7, global chunk jg = jl ^ (r&7).
  int rr = t >> 3;                         // 0..63
  int jg = (t & 7) ^ ((t >> 3) & 7);       // (r&7) == (t>>3)&7 since c*64 % 8 == 0
  int baseX[4], baseWo[4];
  #pragma unroll
  for (int c=0;c<4;c++){
    int r = c*64 + rr;
    baseX[c]  = srcbase<AX>(mt*256 + r) + jg*8;
    baseWo[c] = r*K + jg*8;
  }

  // fragment LDS short-offsets (kk=0); kk=1 is offset ^ 32 (slot bit2 flip)
  int xoff[8], woff[4];
  #pragma unroll
  for (int j=0;j<8;j++){
    int rx = wmb + j*16 + l16; xoff[j] = rx*64 + ((q8 ^ (rx & 7)) << 3);
  }
  #pragma unroll
  for (int i=0;i<4;i++){
    int rw = wnb + i*16 + l16; woff[i] = rw*64 + ((q8 ^ (rw & 7)) << 3);
  }

  // 8 loads/thread per tile (4 X + 4 W)
  #define STAGE_T(a, XS, WS) do { \
    _Pragma("unroll") \
    for (int c=0;c<4;c++){ \
      ASYNC_CP16(xt + baseX[c] + (a)*SA, (XS) + c*4096 + wid*512); \
      ASYNC_CP16(Wp + baseWo[c] + (a)*64, (WS) + c*4096 + wid*512); \
    } } while(0)

  #define COMPUTE_T(XS, WS) do { \
    _Pragma("unroll") \
    for (int kk=0; kk<2; kk++){ \
      short8 wf[4], xf[8]; \
      _Pragma("unroll") \
      for (int i=0;i<4;i++) wf[i] = *(const short8*)&(WS)[woff[i] ^ (kk<<5)]; \
      _Pragma("unroll") \
      for (int j=0;j<8;j++) xf[j] = *(const short8*)&(XS)[xoff[j] ^ (kk<<5)]; \
      _Pragma("unroll") \
      for (int i=0;i<4;i++) \
        _Pragma("unroll") \
        for (int j=0;j<8;j++) \
          acc[i][j] = __builtin_amdgcn_mfma_f32_16x16x32_bf16(wf[i], xf[j], acc[i][j], 0,0,0); \
    } } while(0)

  // prologue: tile0 staged+ready, tile1 in flight (8 outstanding)
  STAGE_T(0, Xs0, Ws0);
  WAITV0;
  __builtin_amdgcn_s_barrier();
  STAGE_T(1, Xs1, Ws1);

  for (int a2 = 0; a2 < 8; a2++){            // tiles 2*a2 (buf0), 2*a2+1 (buf1); 16 total
    COMPUTE_T(Xs0, Ws0);                     // tile 2*a2 (ready by invariant)
    __builtin_amdgcn_s_barrier();            // buf0 free
    if (a2 < 7){ STAGE_T(2*a2+2, Xs0, Ws0); WAITV8; }   // tile 2*a2+1 landed
    else       { WAITV0; }                               // last odd tile landed
    __builtin_amdgcn_s_barrier();            // buf1 ready for all waves
    COMPUTE_T(Xs1, Ws1);                     // tile 2*a2+1
    if (a2 < 7){
      __builtin_amdgcn_s_barrier();          // buf1 free
      STAGE_T(2*a2+3, Xs1, Ws1);
      WAITV8;                                // tile 2*a2+2 landed -> buf0 ready
      __builtin_amdgcn_s_barrier();
    }
  }
  #undef STAGE_T
  #undef COMPUTE_T

  #pragma unroll
  for (int i=0;i<4;i++){
    #pragma unroll
    for (int j=0;j<8;j++){
      int mg = mt*256 + wmb + j*16 + l16;
      if (EPI){
        // AX==2 final pass: decode coords once per 4-wide c chunk
        int d = (mg>>10)&15, h = (mg>>6)&15, tt = mg&63;
        int n0 = nt*256 + wnb + i*16 + q8*4;
        int a = n0 >> 6, c0 = n0 & 63;
        float4 bi = *(const float4*)(Bimg + (((d*16 + h)*16 + a)*64 + c0));
        float4 bp = *(const float4*)(Bpat + (tt*64 + c0));
        float bs0 = bi.x + bp.x, bs1 = bi.y + bp.y, bs2 = bi.z + bp.z, bs3 = bi.w + bp.w;
        #pragma unroll
        for (int rg=0; rg<4; rg++){
          int ng = n0 + rg;
          int idx = tidx<AX>(mg, ng>>6, ng&63);
          float bsum = (rg==0)?bs0:(rg==1)?bs1:(rg==2)?bs2:bs3;
          float y = out[idx] + acc[i][j][rg] + bsum;
          out[idx] = x[idx] + (y >= 0.f ? y : 0.01f*y);
        }
      } else {
        #pragma unroll
        for (int rg=0; rg<4; rg++){
          int ng = nt*256 + wnb + i*16 + q8*4 + rg;
          int idx = tidx<AX>(mg, ng>>6, ng&63);
          out[idx] += acc[i][j][rg];
        }
      }
    }
  }
}

// ---------------- host-side dispatch ----------------
extern "C" void kernel_launch(void* const* d_in, const int* in_sizes, int n_in,
                              void* d_out, int out_size, void* d_ws, size_t ws_size,
                              hipStream_t stream){
  const float* x = (const float*)d_in[0];
  const float* Wsrc[6] = {(const float*)d_in[1], (const float*)d_in[3], (const float*)d_in[5],
                          (const float*)d_in[7], (const float*)d_in[9], (const float*)d_in[11]};
  const float* Bsrc[6] = {(const float*)d_in[2], (const float*)d_in[4], (const float*)d_in[6],
                          (const float*)d_in[8], (const float*)d_in[10], (const float*)d_in[12]};
  float* out = (float*)d_out;
  char* ws = (char*)d_ws;

  const size_t welems[6] = {1024u*1024u, 1024u*1024u, 1024u*1024u,
                            256u*256u, 256u*256u, 256u*256u};
  size_t wOff[6], o = 0;
  for (int i=0;i<6;i++){ wOff[i] = o; o += welems[i]*2; }
  size_t xtOff = (o + 255) & ~(size_t)255;                 // 64 MiB for xT bf16
  size_t bimgOff = xtOff + ((size_t)1u<<25)*2;             // 1 MiB Bimg
  size_t bpatOff = bimgOff + (size_t)16*16*16*64*4;        // 64 KiB Bpat
  unsigned short* xt = (unsigned short*)(ws + xtOff);
  float* Bimg = (float*)(ws + bimgOff);
  float* Bpat = (float*)(ws + bpatOff);
  unsigned short* Wbf[6];
  for (int i=0;i<6;i++) Wbf[i] = (unsigned short*)(ws + wOff[i]);

  castw_all<<<7616,256,0,stream>>>(Wsrc[0],Wsrc[1],Wsrc[2],Wsrc[3],Wsrc[4],Wsrc[5],
                                   Bsrc[0],Bsrc[1],Bsrc[2],Bsrc[3],Bsrc[4],Bsrc[5],
                                   Wbf[0],Wbf[1],Wbf[2],Wbf[3],Wbf[4],Wbf[5],
                                   Bimg, Bpat);
  transpose_cx<<<8192,256,0,stream>>>(x, xt);

  // patches first: single full write of out (3 patch axes fused)
  patch_fused<<<4096,256,0,stream>>>(xt, Wbf[3], Wbf[4], Wbf[5], out);

  // image axes: RMW into out; final axis fuses bias + leaky_relu + residual
  gemm_img<0,0><<<512,512,0,stream>>>(xt, Wbf[0], out, nullptr, nullptr, nullptr);
  gemm_img<1,0><<<512,512,0,stream>>>(xt, Wbf[1], out, nullptr, nullptr, nullptr);
  gemm_img<2,1><<<512,512,0,stream>>>(xt, Wbf[2], out, x, Bimg, Bpat);
}

// Round 7
// 772.606 us; speedup vs baseline: 1.1043x; 1.1043x over previous
//
#include <hip/hip_runtime.h>

typedef __attribute__((ext_vector_type(8))) short short8;
typedef __attribute__((ext_vector_type(4))) float floatx4;

// Original x layout (element offsets): b<<24 | c<<18 | d<<14 | h<<10 | w<<6 | p<<4 | q<<2 | r
// Transposed xT layout (bf16): offset = b<<24 | s<<6 | c, s = d<<14|...|r (same packing).
// Image axes: 0=d 1=h 2=w. Patch axes handled by patch_fused (p,q,r).
// GEMM k = a*64 + c (matches W.reshape(S,C,S,C)).

__device__ __forceinline__ unsigned short f2bf(float f){
  unsigned int u = __float_as_uint(f);
  u += 0x7FFFu + ((u >> 16) & 1u);   // RNE
  return (unsigned short)(u >> 16);
}

// m -> element offset in ORIGINAL layout, given axis value a and channel c (image stores)
template<int AX>
__device__ __forceinline__ int tidx(int m, int a, int c){
  if      (AX==0){ int b=m>>14, t=m&16383;                         return (b<<24)|(c<<18)|(a<<14)|t; }
  else if (AX==1){ int b=m>>14, d=(m>>10)&15, t=m&1023;            return (b<<24)|(c<<18)|(d<<14)|(a<<10)|t; }
  else           { int b=m>>14, d=(m>>10)&15, h=(m>>6)&15, t=m&63; return (b<<24)|(c<<18)|(d<<14)|(h<<10)|(a<<6)|t; }
}

// m -> base element offset in TRANSPOSED layout (a=0, c=0); add a*SA + c.
template<int AX>
__device__ __forceinline__ int srcbase(int m){
  if      (AX==0) return ((m>>14)<<24) | (((m>>10)&15)<<16) | (((m>>6)&15)<<12) | ((m&63)<<6);
  else if (AX==1) return ((m>>14)<<24) | (((m>>10)&15)<<20) | (((m>>6)&15)<<12) | ((m&63)<<6);
  else            return ((m>>14)<<24) | (((m>>10)&15)<<20) | (((m>>6)&15)<<16) | ((m&63)<<6);
}

#define ASYNC_CP16(g, l) \
  __builtin_amdgcn_global_load_lds( \
      (const __attribute__((address_space(1))) unsigned int*)(g), \
      (__attribute__((address_space(3))) unsigned int*)(l), 16, 0, 0)

// ---------------- fused weight cast + bias precombine ----------------
// blocks [0,6144): big W cast; [6144,6528): small W cast;
// [6528,7552): Bimg[d][h][w][c] = bd+bh+bw; [7552,7616): Bpat[t][c] = bpd+bph+bpw
__global__ __launch_bounds__(256) void castw_all(
    const float* __restrict__ wa, const float* __restrict__ wb, const float* __restrict__ wc,
    const float* __restrict__ wd_, const float* __restrict__ we, const float* __restrict__ wf,
    const float* __restrict__ bd_, const float* __restrict__ bh_, const float* __restrict__ bw_,
    const float* __restrict__ bpd_, const float* __restrict__ bph_, const float* __restrict__ bpw_,
    unsigned short* oa, unsigned short* ob, unsigned short* oc,
    unsigned short* od, unsigned short* oe, unsigned short* of_,
    float* __restrict__ Bimg, float* __restrict__ Bpat){
  int blk = blockIdx.x;
  if (blk < 6528){
    const float* src; unsigned short* dst; int idx;
    if (blk < 6144){ int wsel = blk >> 11, loc = blk & 2047;
      src = wsel==0?wa:(wsel==1?wb:wc); dst = wsel==0?oa:(wsel==1?ob:oc);
      idx = loc*256 + threadIdx.x; }
    else { int b2 = blk - 6144, wsel = b2 >> 7, loc = b2 & 127;
      src = wsel==0?wd_:(wsel==1?we:wf); dst = wsel==0?od:(wsel==1?oe:of_);
      idx = loc*256 + threadIdx.x; }
    float2 v = ((const float2*)src)[idx];
    ((unsigned int*)dst)[idx] = (unsigned int)f2bf(v.x) | ((unsigned int)f2bf(v.y) << 16);
  } else if (blk < 7552){
    int idx = (blk - 6528)*256 + threadIdx.x;     // [d][h][w][c]
    int c = idx & 63, wv = (idx>>6)&15, hv = (idx>>10)&15, dv = idx>>14;
    Bimg[idx] = bd_[dv*64+c] + bh_[hv*64+c] + bw_[wv*64+c];
  } else {
    int idx = (blk - 7552)*256 + threadIdx.x;     // [t][c], t = p<<4|q<<2|r
    int c = idx & 63, tt = idx>>6;
    int p = tt>>4, q = (tt>>2)&3, r = tt&3;
    Bpat[idx] = bpd_[p*64+c] + bph_[q*64+c] + bpw_[r*64+c];
  }
}

// ---------------- transpose: x fp32 [b][c][s] -> xT bf16 [b][s][c] ----------------
__global__ __launch_bounds__(256) void transpose_cx(const float* __restrict__ x,
                                                    unsigned short* __restrict__ xt){
  __shared__ float T[64][65];
  int b  = blockIdx.x >> 12;
  int s0 = (blockIdx.x & 4095) * 64;
  int t = threadIdx.x;
  int cr = t >> 4, sq = t & 15;
  #pragma unroll
  for (int it = 0; it < 4; it++){
    int c = it*16 + cr;
    float4 v = *(const float4*)(x + (b<<24) + (c<<18) + s0 + sq*4);
    T[c][sq*4+0]=v.x; T[c][sq*4+1]=v.y; T[c][sq*4+2]=v.z; T[c][sq*4+3]=v.w;
  }
  __syncthreads();
  int sw = t >> 2, cq = t & 3;
  unsigned int pk[8];
  #pragma unroll
  for (int i=0;i<8;i++){
    float f0 = T[cq*16 + 2*i    ][sw];
    float f1 = T[cq*16 + 2*i + 1][sw];
    pk[i] = (unsigned int)f2bf(f0) | ((unsigned int)f2bf(f1) << 16);
  }
  uint4* dst = (uint4*)(xt + (b<<24) + ((s0 + sw)<<6) + cq*16);
  dst[0] = make_uint4(pk[0],pk[1],pk[2],pk[3]);
  dst[1] = make_uint4(pk[4],pk[5],pk[6],pk[7]);
}

// ---------------- fused patch kernel: 3 patch axes, one pass over out ----------------
// Block owns 2 consecutive patches (contiguous 8192 els of xT), staged ONCE into LDS
// (chunk-XOR swizzled so ds_read_b128 for all 3 axes' access patterns is <=2-way).
// Wave w owns own-axis output coord a'=w for each axis. LDS fp32 acc stride 65.
// R7: W (af) loads software-pipelined one kit ahead (static double-state af[2][4],
// fully-unrolled kit loop -> all indices compile-time); row pointers hoisted;
// setprio(1) around each MFMA cluster (T5).
template<int AXI, bool FIRST>
__device__ __forceinline__ void patch_axis(const unsigned short* Xs,
                                           const unsigned short* __restrict__ W,
                                           float* AccL, int w, int l16, int q8){
  floatx4 acc[4][2];
  #pragma unroll
  for (int nt=0;nt<4;nt++)
    #pragma unroll
    for (int mt=0;mt<2;mt++) acc[nt][mt] = (floatx4){0.f,0.f,0.f,0.f};

  const unsigned short* Wn[4];
  #pragma unroll
  for (int nt = 0; nt < 4; nt++){
    int n = w*64 + nt*16 + l16;
    Wn[nt] = W + n*256 + q8*8;
  }
  short8 af[2][4];
  #pragma unroll
  for (int nt = 0; nt < 4; nt++) af[0][nt] = *(const short8*)(Wn[nt]);

  #pragma unroll
  for (int kit = 0; kit < 8; kit++){
    // prefetch next kit's W fragments into the other register bank
    if (kit < 7){
      #pragma unroll
      for (int nt = 0; nt < 4; nt++)
        af[(kit+1)&1][nt] = *(const short8*)(Wn[nt] + (kit+1)*32);
    }
    int a = kit >> 1;
    short8 bf[2];
    int u = (AXI==0) ? (a*16 + l16)
          : (AXI==1) ? ((l16>>2)*16 + a*4 + (l16&3))
                     : ((l16>>2)*16 + (l16&3)*4 + a);
    int jg = ((kit & 1) << 2) + q8;                 // global 16B-chunk index within row
    #pragma unroll
    for (int mt = 0; mt < 2; mt++){
      int r = mt*64 + u;
      int j = jg ^ ((r ^ (r >> 3)) & 7);           // same involution as staging
      bf[mt] = *(const short8*)(Xs + r*64 + j*8);
    }
    __builtin_amdgcn_s_setprio(1);
    #pragma unroll
    for (int nt=0; nt<4; nt++)
      #pragma unroll
      for (int mt=0; mt<2; mt++)
        acc[nt][mt] = __builtin_amdgcn_mfma_f32_16x16x32_bf16(af[kit&1][nt], bf[mt], acc[nt][mt], 0,0,0);
    __builtin_amdgcn_s_setprio(0);
  }

  int uo = (AXI==0) ? (w*16 + l16)
         : (AXI==1) ? ((l16>>2)*16 + w*4 + (l16&3))
                    : ((l16>>2)*16 + (l16&3)*4 + w);
  #pragma unroll
  for (int nt=0; nt<4; nt++)
    #pragma unroll
    for (int mt=0; mt<2; mt++){
      float* p = AccL + (mt*64 + uo)*65 + nt*16 + q8*4;
      #pragma unroll
      for (int rg=0; rg<4; rg++){
        if (FIRST) p[rg]  = acc[nt][mt][rg];
        else       p[rg] += acc[nt][mt][rg];
      }
    }
}

__global__ __launch_bounds__(256) void patch_fused(const unsigned short* __restrict__ xt,
    const unsigned short* __restrict__ Wp_, const unsigned short* __restrict__ Wq_,
    const unsigned short* __restrict__ Wr_, float* __restrict__ out){
  __shared__ float AccL[2*64*65];            // 33.28 KB
  __shared__ unsigned short Xs[8192];        // 16 KB: 128 rows x 64 shorts, chunk-swizzled
  int pp = blockIdx.x;
  int b = pp >> 11, dpair = pp & 2047;
  const unsigned short* xp = xt + (b<<24) + dpair*8192;
  int t = threadIdx.x, w = t>>6, lane = t&63, q8 = lane>>4, l16 = lane&15;

  // stage 2 patches (1024 x 16B chunks) via async copy; inverse-swizzled global source,
  // linear LDS dest (wave-uniform base + lane*16 appended by HW)
  #pragma unroll
  for (int i = 0; i < 4; i++){
    int L = i*256 + t;                       // LDS chunk index this lane fills
    int r = L >> 3, jl = L & 7;
    int jg = jl ^ ((r ^ (r >> 3)) & 7);
    ASYNC_CP16(xp + r*64 + jg*8, Xs + i*2048 + w*512);
  }
  __syncthreads();

  patch_axis<0,true >(Xs, Wp_, AccL, w, l16, q8);
  __syncthreads();
  patch_axis<1,false>(Xs, Wq_, AccL, w, l16, q8);
  __syncthreads();
  patch_axis<2,false>(Xs, Wr_, AccL, w, l16, q8);
  __syncthreads();

  int sbase = dpair*128;                     // s = dpair*2*64 + pt*64 + u
  #pragma unroll
  for (int it = 0; it < 32; it++){
    int lin = it*256 + t;
    int c = lin >> 7, rem = lin & 127, pt = rem >> 6, u = rem & 63;
    out[(b<<24) | (c<<18) | (sbase + pt*64 + u)] = AccL[(pt*64+u)*65 + c];
  }
}

// ---------------- image GEMM: out[n=(a',c'), m] += sum_k W[n][k] * xT[m][k] ----------------
// 256x256 tile, 512 threads (8 waves, wave sub-tile 128m x 64n). R7: T3-minimum loop --
// stage-at-top into the buffer freed by the previous barrier, ONE barrier + ONE vmcnt(0)
// per K-tile (wait margin = one full compute phase), setprio(1/0) around MFMA clusters
// (T5: 8 staggered waves give the scheduler role diversity).
// XCD grouping: the 4 nt-blocks sharing one X stripe land on the same XCD (stride-8).
// BK=64, 128B LDS rows, slot-XOR swizzle j ^= (r&7): ds_read_b128 is 2-way max (free).
// EPI: fused final epilogue  out = x + leaky(out + acc + Bimg + Bpat)  (AX==2 only).
#define WAITV0 asm volatile("s_waitcnt vmcnt(0)" ::: "memory")

template<int AX, int EPI>
__global__ __launch_bounds__(512, 2) void gemm_img(const unsigned short* __restrict__ xt,
                                                   const unsigned short* __restrict__ Wbf,
                                                   float* __restrict__ out,
                                                   const float* __restrict__ x,
                                                   const float* __restrict__ Bimg,
                                                   const float* __restrict__ Bpat){
  constexpr int K  = 1024;
  constexpr int SA = (AX==0)?(1<<20):(AX==1)?(1<<16):(1<<12);
  // 512 blocks = 128 mt x 4 nt; same-mt quads share an XCD (bids differ by 8).
  int bid = blockIdx.x;
  int mt = (bid >> 5) * 8 + (bid & 7);     // 0..127
  int nt = (bid >> 3) & 3;                 // 0..3

  __shared__ unsigned short Xs0[256*64], Ws0[256*64];   // 32 KB each
  __shared__ unsigned short Xs1[256*64], Ws1[256*64];   // 128 KB total -> 1 block/CU

  int t = threadIdx.x, lane = t & 63, wid = t >> 6;
  int wnb = (wid & 3) << 6;                // wave n offset: 0,64,128,192
  int wmb = (wid >> 2) << 7;               // wave m offset: 0,128
  int q8 = lane >> 4, l16 = lane & 15;

  floatx4 acc[4][8];
  #pragma unroll
  for (int i=0;i<4;i++)
    #pragma unroll
    for (int j=0;j<8;j++) acc[i][j] = (floatx4){0.f,0.f,0.f,0.f};

  const unsigned short* Wp = Wbf + (size_t)nt*256*K;

  // staging: thread t fills LDS chunk L = c*512 + t (c = 0..3);
  // row r = c*64 + (t>>3), local slot jl = t&7, global chunk jg = jl ^ (r&7).
  int rr = t >> 3;                         // 0..63
  int jg = (t & 7) ^ ((t >> 3) & 7);       // (r&7) == (t>>3)&7 since c*64 % 8 == 0
  int baseX[4], baseWo[4];
  #pragma unroll
  for (int c=0;c<4;c++){
    int r = c*64 + rr;
    baseX[c]  = srcbase<AX>(mt*256 + r) + jg*8;
    baseWo[c] = r*K + jg*8;
  }

  // fragment LDS short-offsets (kk=0); kk=1 is offset ^ 32 (slot bit2 flip)
  int xoff[8], woff[4];
  #pragma unroll
  for (int j=0;j<8;j++){
    int rx = wmb + j*16 + l16; xoff[j] = rx*64 + ((q8 ^ (rx & 7)) << 3);
  }
  #pragma unroll
  for (int i=0;i<4;i++){
    int rw = wnb + i*16 + l16; woff[i] = rw*64 + ((q8 ^ (rw & 7)) << 3);
  }

  // 8 loads/thread per tile (4 X + 4 W)
  #define STAGE_T(a, XS, WS) do { \
    _Pragma("unroll") \
    for (int c=0;c<4;c++){ \
      ASYNC_CP16(xt + baseX[c] + (a)*SA, (XS) + c*4096 + wid*512); \
      ASYNC_CP16(Wp + baseWo[c] + (a)*64, (WS) + c*4096 + wid*512); \
    } } while(0)

  #define COMPUTE_T(XS, WS) do { \
    _Pragma("unroll") \
    for (int kk=0; kk<2; kk++){ \
      short8 wf[4], xf[8]; \
      _Pragma("unroll") \
      for (int i=0;i<4;i++) wf[i] = *(const short8*)&(WS)[woff[i] ^ (kk<<5)]; \
      _Pragma("unroll") \
      for (int j=0;j<8;j++) xf[j] = *(const short8*)&(XS)[xoff[j] ^ (kk<<5)]; \
      __builtin_amdgcn_s_setprio(1); \
      _Pragma("unroll") \
      for (int i=0;i<4;i++) \
        _Pragma("unroll") \
        for (int j=0;j<8;j++) \
          acc[i][j] = __builtin_amdgcn_mfma_f32_16x16x32_bf16(wf[i], xf[j], acc[i][j], 0,0,0); \
      __builtin_amdgcn_s_setprio(0); \
    } } while(0)

  // prologue: tile0 staged+ready, nothing in flight
  STAGE_T(0, Xs0, Ws0);
  WAITV0;
  __builtin_amdgcn_s_barrier();

  // T3-min: per tile {stage next -> freed buffer; compute current; vmcnt(0); barrier}
  for (int a2 = 0; a2 < 8; a2++){            // tiles 2*a2 (buf0), 2*a2+1 (buf1); 16 total
    STAGE_T(2*a2+1, Xs1, Ws1);               // buf1 freed by previous iteration's barrier
    COMPUTE_T(Xs0, Ws0);                     // tile 2*a2
    WAITV0;                                  // tile 2*a2+1 landed (margin: compute above)
    __builtin_amdgcn_s_barrier();
    if (a2 < 7){
      STAGE_T(2*a2+2, Xs0, Ws0);             // buf0 freed by the barrier above
    }
    COMPUTE_T(Xs1, Ws1);                     // tile 2*a2+1
    if (a2 < 7){
      WAITV0;                                // tile 2*a2+2 landed
      __builtin_amdgcn_s_barrier();
    }
  }
  #undef STAGE_T
  #undef COMPUTE_T

  #pragma unroll
  for (int i=0;i<4;i++){
    #pragma unroll
    for (int j=0;j<8;j++){
      int mg = mt*256 + wmb + j*16 + l16;
      if (EPI){
        // AX==2 final pass: decode coords once per 4-wide c chunk
        int d = (mg>>10)&15, h = (mg>>6)&15, tt = mg&63;
        int n0 = nt*256 + wnb + i*16 + q8*4;
        int a = n0 >> 6, c0 = n0 & 63;
        float4 bi = *(const float4*)(Bimg + (((d*16 + h)*16 + a)*64 + c0));
        float4 bp = *(const float4*)(Bpat + (tt*64 + c0));
        float bs0 = bi.x + bp.x, bs1 = bi.y + bp.y, bs2 = bi.z + bp.z, bs3 = bi.w + bp.w;
        #pragma unroll
        for (int rg=0; rg<4; rg++){
          int ng = n0 + rg;
          int idx = tidx<AX>(mg, ng>>6, ng&63);
          float bsum = (rg==0)?bs0:(rg==1)?bs1:(rg==2)?bs2:bs3;
          float y = out[idx] + acc[i][j][rg] + bsum;
          out[idx] = x[idx] + (y >= 0.f ? y : 0.01f*y);
        }
      } else {
        #pragma unroll
        for (int rg=0; rg<4; rg++){
          int ng = nt*256 + wnb + i*16 + q8*4 + rg;
          int idx = tidx<AX>(mg, ng>>6, ng&63);
          out[idx] += acc[i][j][rg];
        }
      }
    }
  }
}

// ---------------- host-side dispatch ----------------
extern "C" void kernel_launch(void* const* d_in, const int* in_sizes, int n_in,
                              void* d_out, int out_size, void* d_ws, size_t ws_size,
                              hipStream_t stream){
  const float* x = (const float*)d_in[0];
  const float* Wsrc[6] = {(const float*)d_in[1], (const float*)d_in[3], (const float*)d_in[5],
                          (const float*)d_in[7], (const float*)d_in[9], (const float*)d_in[11]};
  const float* Bsrc[6] = {(const float*)d_in[2], (const float*)d_in[4], (const float*)d_in[6],
                          (const float*)d_in[8], (const float*)d_in[10], (const float*)d_in[12]};
  float* out = (float*)d_out;
  char* ws = (char*)d_ws;

  const size_t welems[6] = {1024u*1024u, 1024u*1024u, 1024u*1024u,
                            256u*256u, 256u*256u, 256u*256u};
  size_t wOff[6], o = 0;
  for (int i=0;i<6;i++){ wOff[i] = o; o += welems[i]*2; }
  size_t xtOff = (o + 255) & ~(size_t)255;                 // 64 MiB for xT bf16
  size_t bimgOff = xtOff + ((size_t)1u<<25)*2;             // 1 MiB Bimg
  size_t bpatOff = bimgOff + (size_t)16*16*16*64*4;        // 64 KiB Bpat
  unsigned short* xt = (unsigned short*)(ws + xtOff);
  float* Bimg = (float*)(ws + bimgOff);
  float* Bpat = (float*)(ws + bpatOff);
  unsigned short* Wbf[6];
  for (int i=0;i<6;i++) Wbf[i] = (unsigned short*)(ws + wOff[i]);

  castw_all<<<7616,256,0,stream>>>(Wsrc[0],Wsrc[1],Wsrc[2],Wsrc[3],Wsrc[4],Wsrc[5],
                                   Bsrc[0],Bsrc[1],Bsrc[2],Bsrc[3],Bsrc[4],Bsrc[5],
                                   Wbf[0],Wbf[1],Wbf[2],Wbf[3],Wbf[4],Wbf[5],
                                   Bimg, Bpat);
  transpose_cx<<<8192,256,0,stream>>>(x, xt);

  // patches first: single full write of out (3 patch axes fused)
  patch_fused<<<4096,256,0,stream>>>(xt, Wbf[3], Wbf[4], Wbf[5], out);

  // image axes: RMW into out; final axis fuses bias + leaky_relu + residual
  gemm_img<0,0><<<512,512,0,stream>>>(xt, Wbf[0], out, nullptr, nullptr, nullptr);
  gemm_img<1,0><<<512,512,0,stream>>>(xt, Wbf[1], out, nullptr, nullptr, nullptr);
  gemm_img<2,1><<<512,512,0,stream>>>(xt, Wbf[2], out, x, Bimg, Bpat);
}